// Round 7
// baseline (507.064 us; speedup 1.0000x reference)
//
#include <hip/hip_runtime.h>
#include <math.h>

#define N_NODES 50000
#define N_EDGES 300000
#define BN_EPS 1e-5f
#define NEG_SLOPE 0.2f

// 50000 rows pad to 3128 row-blocks of 16 (50048)
#define RB_COUNT 3128
#define SCAN_TILES 49   // 49*1024 = 50176 >= N_NODES

typedef short bf8v __attribute__((ext_vector_type(8)));
typedef float f4v __attribute__((ext_vector_type(4)));
typedef unsigned short u8v __attribute__((ext_vector_type(8)));

__device__ inline unsigned short f2bf(float f) {
    union { float f; unsigned u; } c; c.f = f;
    unsigned r = c.u + 0x7fffu + ((c.u >> 16) & 1u);
    return (unsigned short)(r >> 16);
}
__device__ inline float bf2f(unsigned short u) {
    union { unsigned u; float f; } c; c.u = ((unsigned)u) << 16;
    return c.f;
}

// async global->LDS DMA, 16B per lane; LDS dest = ldsbase + lane*16 (wave-uniform base)
__device__ inline void async_copy16(void* lds, const void* g) {
    __builtin_amdgcn_global_load_lds(
        (const __attribute__((address_space(1))) unsigned int*)g,
        (__attribute__((address_space(3))) unsigned int*)lds, 16, 0, 0);
}

// ---------------- BN0 (5 columns), grid-parallel ----------------
__global__ void bn0_reduce(const float* __restrict__ h, float* __restrict__ acc /*[10]*/) {
    __shared__ float lds[4][10];
    int tid = threadIdx.x;
    int lane = tid & 63, wave = tid >> 6;
    float ls[5] = {0,0,0,0,0}, lq[5] = {0,0,0,0,0};
    for (int r = blockIdx.x * 256 + tid; r < N_NODES; r += 128 * 256) {
        #pragma unroll
        for (int k = 0; k < 5; k++) {
            float v = h[r*5 + k];
            ls[k] += v; lq[k] += v*v;
        }
    }
    #pragma unroll
    for (int k = 0; k < 5; k++) {
        #pragma unroll
        for (int m = 1; m <= 32; m <<= 1) {
            ls[k] += __shfl_xor(ls[k], m, 64);
            lq[k] += __shfl_xor(lq[k], m, 64);
        }
    }
    if (lane == 0) {
        #pragma unroll
        for (int k = 0; k < 5; k++) { lds[wave][k] = ls[k]; lds[wave][5+k] = lq[k]; }
    }
    __syncthreads();
    if (tid < 10) {
        float s = lds[0][tid] + lds[1][tid] + lds[2][tid] + lds[3][tid];
        atomicAdd(&acc[tid], s);
    }
}

__global__ void bn0_finalize(const float* __restrict__ acc, const float* __restrict__ g,
                             const float* __restrict__ b, float* __restrict__ ss) {
    int tid = threadIdx.x;
    if (tid < 5) {
        float mean = acc[tid] * (1.f / N_NODES);
        float var  = acc[5 + tid] * (1.f / N_NODES) - mean*mean;
        float sc = g[tid] * rsqrtf(var + BN_EPS);
        ss[tid]     = sc;
        ss[5 + tid] = b[tid] - mean * sc;
    }
}

__global__ void bn0_apply(const float* __restrict__ h, const float* __restrict__ ss,
                          float* __restrict__ x0) {
    int i = blockIdx.x * blockDim.x + threadIdx.x;
    if (i < N_NODES * 5) {
        int k = i % 5;
        x0[i] = h[i] * ss[k] + ss[5 + k];
    }
}

// ---------------- CSR build by dst ----------------
__global__ void edge_count(const int* __restrict__ dst, int* __restrict__ count) {
    int e = blockIdx.x * blockDim.x + threadIdx.x;
    if (e < N_EDGES) atomicAdd(&count[dst[e]], 1);
}

// two-level scan: per-tile local exclusive scan + tile totals
__global__ void local_scan(const int* __restrict__ count, int* __restrict__ offsets,
                           int* __restrict__ tileSum) {
    __shared__ int lds[1024];
    int tid = threadIdx.x;
    int i = blockIdx.x * 1024 + tid;
    int v = (i < N_NODES) ? count[i] : 0;
    lds[tid] = v;
    __syncthreads();
    #pragma unroll
    for (int off = 1; off < 1024; off <<= 1) {
        int t = (tid >= off) ? lds[tid - off] : 0;
        __syncthreads();
        lds[tid] += t;
        __syncthreads();
    }
    if (i < N_NODES) offsets[i] = lds[tid] - v;   // local exclusive
    if (tid == 1023) tileSum[blockIdx.x] = lds[1023];
}

__global__ void tile_scan(const int* __restrict__ tileSum, int* __restrict__ tilePrefix,
                          int* __restrict__ offsets) {
    int lane = threadIdx.x;
    int v = (lane < SCAN_TILES) ? tileSum[lane] : 0;
    int inc = v;
    #pragma unroll
    for (int off = 1; off < 64; off <<= 1) {
        int t = __shfl_up(inc, off, 64);
        if (lane >= off) inc += t;
    }
    int excl = inc - v;
    if (lane < SCAN_TILES) tilePrefix[lane] = excl;
    if (lane == SCAN_TILES - 1) offsets[N_NODES] = inc;
}

__global__ void add_prefix(int* __restrict__ offsets, const int* __restrict__ tilePrefix,
                           int* __restrict__ cursor) {
    int i = blockIdx.x * 1024 + threadIdx.x;
    if (i < N_NODES) {
        int o = offsets[i] + tilePrefix[blockIdx.x];
        offsets[i] = o;
        cursor[i] = o;
    }
}

// scatter edge ids into CSR order; also materialize src and edge-weight in CSR order
__global__ void edge_scatter(const int* __restrict__ dst, const int* __restrict__ src,
                             const float* __restrict__ ew, int* __restrict__ cursor,
                             int* __restrict__ srcp, float* __restrict__ ewp) {
    int e = blockIdx.x * blockDim.x + threadIdx.x;
    if (e < N_EDGES) {
        int pos = atomicAdd(&cursor[dst[e]], 1);
        srcp[pos] = src[e];
        ewp[pos] = ew[e];
    }
}

// ---------------- conv1 linear (K=5), bf16 output ----------------
__global__ void gemm_k5(const float* __restrict__ x0,
                        const float* __restrict__ Wl, const float* __restrict__ bl,
                        const float* __restrict__ Wr, const float* __restrict__ br,
                        unsigned short* __restrict__ xl, unsigned short* __restrict__ xr) {
    int n = blockIdx.x;
    int c = threadIdx.x;
    float a0 = x0[n*5+0], a1 = x0[n*5+1], a2 = x0[n*5+2], a3 = x0[n*5+3], a4 = x0[n*5+4];
    float l = bl[c] + a0*Wl[c] + a1*Wl[256+c] + a2*Wl[512+c] + a3*Wl[768+c] + a4*Wl[1024+c];
    float r = br[c] + a0*Wr[c] + a1*Wr[256+c] + a2*Wr[512+c] + a3*Wr[768+c] + a4*Wr[1024+c];
    xl[n*256 + c] = f2bf(l);
    xr[n*256 + c] = f2bf(r);
}

// ---------------- pack X with fused BN1+ReLU (fp32 xB -> bf16 MFMA A-fragment order) ----
__global__ void pack_x_bn(const float* __restrict__ x,
                          const float* __restrict__ sum, const float* __restrict__ sumsq,
                          const float* __restrict__ g, const float* __restrict__ b,
                          unsigned short* __restrict__ ap) {
    int t = blockIdx.x * 256 + threadIdx.x;   // RB_COUNT*8*64 = 1601536 threads exact
    int lane = t & 63;
    int kc = (t >> 6) & 7;
    int rb = t >> 9;
    int row = rb * 16 + (lane & 15);
    int k0 = kc * 32 + (lane >> 4) * 8;
    union { unsigned short h[8]; uint4 u; } tmp;
    if (row < N_NODES) {
        const float* s = x + (size_t)row * 256 + k0;
        #pragma unroll
        for (int j = 0; j < 8; j++) {
            int c = k0 + j;
            float mean = sum[c] * (1.f / N_NODES);
            float var  = sumsq[c] * (1.f / N_NODES) - mean*mean;
            float sc = g[c] * rsqrtf(var + BN_EPS);
            float v = (s[j] - mean) * sc + b[c];
            v = v > 0.f ? v : 0.f;
            tmp.h[j] = f2bf(v);
        }
    } else {
        #pragma unroll
        for (int j = 0; j < 8; j++) tmp.h[j] = 0;
    }
    *reinterpret_cast<uint4*>(ap + (size_t)t * 8) = tmp.u;
}

// ---------------- pack W for both convs (fp32 -> bf16 MFMA B-fragment order) ----------------
__global__ void pack_w(const float* __restrict__ Wl0, const float* __restrict__ Wr0,
                       const float* __restrict__ Wl1, const float* __restrict__ Wr1,
                       unsigned short* __restrict__ bp) {
    int t = blockIdx.x * 256 + threadIdx.x;   // 2*8*32*64 = 32768 threads exact
    int lane = t & 63;
    int nt = (t >> 6) & 31;
    int kc = (t >> 11) & 7;
    int conv = t >> 14;
    int col = nt * 16 + (lane & 15);
    int k0 = kc * 32 + (lane >> 4) * 8;
    const float* W = conv ? (col < 256 ? Wl1 : Wr1) : (col < 256 ? Wl0 : Wr0);
    int c = col & 255;
    union { unsigned short h[8]; uint4 u; } tmp;
    #pragma unroll
    for (int j = 0; j < 8; j++) tmp.h[j] = f2bf(W[(size_t)(k0 + j) * 256 + c]);
    *reinterpret_cast<uint4*>(bp + (size_t)t * 8) = tmp.u;
}

// ---------------- big linear via MFMA, LDS-staged B (double-buffered), bf16 output -------
__global__ __launch_bounds__(512) void gemm_mfma(const unsigned short* __restrict__ ap,
        const unsigned short* __restrict__ bp,
        const float* __restrict__ bl, const float* __restrict__ br,
        unsigned short* __restrict__ xl, unsigned short* __restrict__ xr) {
    __shared__ unsigned short Bs[2][32][512];   // [buf][frag f=h*16+t][lane*8]
    int lane = threadIdx.x & 63;
    int wave = threadIdx.x >> 6;
    int h = wave & 1;
    int rb = blockIdx.x * 4 + (wave >> 1);

    const unsigned short* aptr = ap + (size_t)rb * 4096 + lane * 8;
    const unsigned short* bsrc = bp + lane * 8;

    // stage B[kc] into Bs[buf]: this wave's 4 frags (f = wave*4 + j; f -> offset f*512)
    auto stage = [&](int buf, int kc) {
        #pragma unroll
        for (int j = 0; j < 4; j++) {
            int f = wave * 4 + j;
            async_copy16(&Bs[buf][f][lane * 8], bsrc + (size_t)kc * 16384 + f * 512);
        }
    };
    stage(0, 0);

    // preload all A fragments (8 kc x 16B/lane = 32 VGPRs)
    bf8v a[8];
    #pragma unroll
    for (int kc = 0; kc < 8; kc++) a[kc] = *reinterpret_cast<const bf8v*>(aptr + kc * 512);

    f4v acc[16];
    #pragma unroll
    for (int t = 0; t < 16; t++) acc[t] = (f4v){0.f, 0.f, 0.f, 0.f};

    for (int kc = 0; kc < 8; kc++) {
        __syncthreads();                       // staging of buf kc&1 complete; prev buf free
        if (kc < 7) stage((kc + 1) & 1, kc + 1);
        const unsigned short* bb = &Bs[kc & 1][h * 16][lane * 8];
        #pragma unroll
        for (int t = 0; t < 16; t++) {
            bf8v b = *reinterpret_cast<const bf8v*>(bb + t * 512);
            acc[t] = __builtin_amdgcn_mfma_f32_16x16x32_bf16(a[kc], b, acc[t], 0, 0, 0);
        }
    }

    int c15 = lane & 15;
    int row0 = rb * 16 + (lane >> 4) * 4;
    unsigned short* outp = h ? xr : xl;
    const float* bias = h ? br : bl;
    #pragma unroll
    for (int t = 0; t < 16; t++) {
        int col = t * 16 + c15;
        float bv = bias[col];
        #pragma unroll
        for (int r = 0; r < 4; r++) {
            int row = row0 + r;
            if (row < N_NODES) outp[(size_t)row * 256 + col] = f2bf(acc[t][r] + bv);
        }
    }
}

// ---------------- fused GATv2 edge phase: alpha + online-softmax + aggregate ----------
// one wave per node, TWO edge streams per wave (lanes 0-31: even edges, 32-63: odd edges).
// Within a stream: 16 lanes per head, 8 channels per lane (16B gathers).
// Streams keep independent online-softmax state, merged at the end via shfl_xor 32.
template <int CONCAT>
__global__ void agg_fused(const unsigned short* __restrict__ xl,
                          const unsigned short* __restrict__ xr,
                          const float* __restrict__ We, const float* __restrict__ att,
                          const int* __restrict__ offsets, const int* __restrict__ srcp,
                          const float* __restrict__ ewp, const float* __restrict__ bias,
                          float* __restrict__ out) {
    int n = blockIdx.x * 4 + (threadIdx.x >> 6);
    int lane = threadIdx.x & 63;
    if (n >= N_NODES) return;
    int half = lane >> 5;                              // edge stream (even/odd)
    int sub  = lane & 31;
    int cb   = (sub >> 4) * 128 + (sub & 15) * 8;      // 8-channel base in [0,256)
    float wv[8], av[8], rv[8];
    *(float4*)&wv[0] = *(const float4*)(We + cb);
    *(float4*)&wv[4] = *(const float4*)(We + cb + 4);
    *(float4*)&av[0] = *(const float4*)(att + cb);
    *(float4*)&av[4] = *(const float4*)(att + cb + 4);
    u8v r8 = *(const u8v*)(xr + (size_t)n * 256 + cb);
    #pragma unroll
    for (int j = 0; j < 8; j++) rv[j] = bf2f(r8[j]);
    int beg = offsets[n], end = offsets[n + 1];
    float mrun = -1e30f, den = 0.f;
    float acc[8];
    #pragma unroll
    for (int j = 0; j < 8; j++) acc[j] = 0.f;

    int i = beg + half;
    int sN = 0; float wN = 0.f;
    u8v lN;
    #pragma unroll
    for (int j = 0; j < 8; j++) lN[j] = 0;
    if (i < end) {
        sN = srcp[i]; wN = ewp[i];
        lN = *(const u8v*)(xl + (size_t)sN * 256 + cb);
    }
    for (; i < end; i += 2) {
        u8v l8 = lN; float w = wN;
        int nx = i + 2;
        if (nx < end) {                              // distance-1 prefetch
            sN = srcp[nx]; wN = ewp[nx];
            lN = *(const u8v*)(xl + (size_t)sN * 256 + cb);
        }
        float lv[8];
        float a = 0.f;
        #pragma unroll
        for (int j = 0; j < 8; j++) {
            lv[j] = bf2f(l8[j]);
            float v = lv[j] + rv[j] + w * wv[j];
            v = fmaxf(v, NEG_SLOPE * v);             // leaky relu (slope<1)
            a += v * av[j];
        }
        a += __shfl_xor(a, 1, 64);
        a += __shfl_xor(a, 2, 64);
        a += __shfl_xor(a, 4, 64);
        a += __shfl_xor(a, 8, 64);                   // per-head alpha (16-lane groups)
        float nm = fmaxf(mrun, a);
        float scl = __expf(mrun - nm);
        float p = __expf(a - nm);
        den = den * scl + p;
        #pragma unroll
        for (int j = 0; j < 8; j++) acc[j] = acc[j] * scl + p * lv[j];
        mrun = nm;
    }
    // merge even/odd streams
    {
        float mo  = __shfl_xor(mrun, 32, 64);
        float dno = __shfl_xor(den, 32, 64);
        float nm = fmaxf(mrun, mo);
        float s0 = __expf(mrun - nm);
        float s1 = __expf(mo - nm);
        den = den * s0 + dno * s1;
        #pragma unroll
        for (int j = 0; j < 8; j++) {
            float ao = __shfl_xor(acc[j], 32, 64);
            acc[j] = acc[j] * s0 + ao * s1;
        }
    }
    float inv = 1.f / (den + 1e-16f);
    if (CONCAT) {
        if (lane < 32) {
            float o[8];
            #pragma unroll
            for (int j = 0; j < 8; j++) o[j] = acc[j] * inv + bias[cb + j];
            *(float4*)(out + (size_t)n * 256 + cb)     = *(float4*)&o[0];
            *(float4*)(out + (size_t)n * 256 + cb + 4) = *(float4*)&o[4];
        }
    } else {
        float o[8];
        #pragma unroll
        for (int j = 0; j < 8; j++) o[j] = acc[j] * inv;
        float po[8];
        #pragma unroll
        for (int j = 0; j < 8; j++) po[j] = __shfl_xor(o[j], 16, 64);  // other head, same ch
        if (lane < 16) {
            int c0 = (lane & 15) * 8;
            float r[8];
            #pragma unroll
            for (int j = 0; j < 8; j++) r[j] = (o[j] + po[j]) * 0.5f + bias[c0 + j];
            *(float4*)(out + (size_t)n * 128 + c0)     = *(float4*)&r[0];
            *(float4*)(out + (size_t)n * 128 + c0 + 4) = *(float4*)&r[4];
        }
    }
}

// ---------------- BN1 stats over [N,256], occupancy-fixed ----------------
// 782 blocks x 64 rows; thread = (4-col group via float4, row phase = tid>>6).
// LDS cross-wave reduce, then 512 atomicAdds per block.
__global__ void bn1_reduce(const float* __restrict__ x, float* __restrict__ sum,
                           float* __restrict__ sumsq) {
    __shared__ float lds[256][8];
    int tid = threadIdx.x;
    int cg = tid & 63;           // col group: cols cg*4 .. cg*4+3
    int ph = tid >> 6;           // row phase 0..3
    int r0 = blockIdx.x * 64;
    float s[4] = {0,0,0,0}, q[4] = {0,0,0,0};
    #pragma unroll
    for (int it = 0; it < 16; it++) {
        int row = r0 + it * 4 + ph;
        if (row < N_NODES) {
            float4 v = *(const float4*)(x + (size_t)row * 256 + cg * 4);
            s[0] += v.x; s[1] += v.y; s[2] += v.z; s[3] += v.w;
            q[0] += v.x*v.x; q[1] += v.y*v.y; q[2] += v.z*v.z; q[3] += v.w*v.w;
        }
    }
    #pragma unroll
    for (int j = 0; j < 4; j++) { lds[tid][j] = s[j]; lds[tid][4+j] = q[j]; }
    __syncthreads();
    if (tid < 64) {
        #pragma unroll
        for (int j = 0; j < 4; j++) {
            float ss = lds[tid][j] + lds[tid+64][j] + lds[tid+128][j] + lds[tid+192][j];
            float qq = lds[tid][4+j] + lds[tid+64][4+j] + lds[tid+128][4+j] + lds[tid+192][4+j];
            atomicAdd(&sum[cg*4 + j], ss);
            atomicAdd(&sumsq[cg*4 + j], qq);
        }
    }
}

extern "C" void kernel_launch(void* const* d_in, const int* in_sizes, int n_in,
                              void* d_out, int out_size, void* d_ws, size_t ws_size,
                              hipStream_t stream) {
    const float* h          = (const float*)d_in[0];
    const int*   edge_index = (const int*)d_in[1];
    const int*   src = edge_index;
    const int*   dst = edge_index + N_EDGES;
    const float* ew   = (const float*)d_in[2];
    const float* bn0g = (const float*)d_in[3];
    const float* bn0b = (const float*)d_in[4];
    const float* bn1g = (const float*)d_in[5];
    const float* bn1b = (const float*)d_in[6];
    const float* c1_Wl = (const float*)d_in[7];
    const float* c1_bl = (const float*)d_in[8];
    const float* c1_Wr = (const float*)d_in[9];
    const float* c1_br = (const float*)d_in[10];
    const float* c1_We = (const float*)d_in[11];
    const float* c1_att = (const float*)d_in[12];
    const float* c1_bias = (const float*)d_in[13];
    const float* mu_Wl = (const float*)d_in[14];
    const float* mu_bl = (const float*)d_in[15];
    const float* mu_Wr = (const float*)d_in[16];
    const float* mu_br = (const float*)d_in[17];
    const float* mu_We = (const float*)d_in[18];
    const float* mu_att = (const float*)d_in[19];
    const float* mu_bias = (const float*)d_in[20];
    const float* ls_Wl = (const float*)d_in[21];
    const float* ls_bl = (const float*)d_in[22];
    const float* ls_Wr = (const float*)d_in[23];
    const float* ls_br = (const float*)d_in[24];
    const float* ls_We = (const float*)d_in[25];
    const float* ls_att = (const float*)d_in[26];
    const float* ls_bias = (const float*)d_in[27];

    float* out_mu = (float*)d_out;
    float* out_ls = (float*)d_out + (size_t)N_NODES * 128;

    // workspace carve-up (256B aligned blocks)
    char* ws = (char*)d_ws;
    size_t off = 0;
    auto alloc = [&](size_t bytes) -> void* {
        void* p = ws + off;
        off += (bytes + 255) / 256 * 256;
        return p;
    };
    float* x0      = (float*)alloc((size_t)N_NODES * 5 * 4);
    unsigned short* xl = (unsigned short*)alloc((size_t)N_NODES * 256 * 2);
    unsigned short* xr = (unsigned short*)alloc((size_t)N_NODES * 256 * 2);
    float* xB      = (float*)alloc((size_t)N_NODES * 256 * 4);
    float* bn0acc  = (float*)alloc(10 * 4);
    float* bn0ss   = (float*)alloc(10 * 4);
    float* bn1sum  = (float*)alloc(256 * 4);
    float* bn1sq   = (float*)alloc(256 * 4);
    int*   count   = (int*)alloc((size_t)N_NODES * 4);
    int*   offsets = (int*)alloc((size_t)(N_NODES + 1) * 4);
    int*   cursor  = (int*)alloc((size_t)N_NODES * 4);
    int*   srcp    = (int*)alloc((size_t)N_EDGES * 4);
    float* ewp     = (float*)alloc((size_t)N_EDGES * 4);
    int*   tileSum = (int*)alloc((size_t)SCAN_TILES * 4);
    int*   tilePre = (int*)alloc((size_t)SCAN_TILES * 4);
    unsigned short* Apack = (unsigned short*)alloc((size_t)RB_COUNT * 4096 * 2);  // 25.6 MB
    unsigned short* Bpack = (unsigned short*)alloc((size_t)2 * 131072 * 2);       // 512 KB

    hipMemsetAsync(count, 0, (size_t)N_NODES * 4, stream);
    hipMemsetAsync(bn0acc, 0, 10 * 4, stream);
    hipMemsetAsync(bn1sum, 0, 256 * 4, stream);
    hipMemsetAsync(bn1sq, 0, 256 * 4, stream);

    // BN0 (grid-parallel)
    bn0_reduce<<<128, 256, 0, stream>>>(h, bn0acc);
    bn0_finalize<<<1, 64, 0, stream>>>(bn0acc, bn0g, bn0b, bn0ss);
    bn0_apply<<<(N_NODES * 5 + 255) / 256, 256, 0, stream>>>(h, bn0ss, x0);

    // CSR by dst (shared by all 3 convs) — two-level parallel scan
    edge_count<<<(N_EDGES + 255) / 256, 256, 0, stream>>>(dst, count);
    local_scan<<<SCAN_TILES, 1024, 0, stream>>>(count, offsets, tileSum);
    tile_scan<<<1, 64, 0, stream>>>(tileSum, tilePre, offsets);
    add_prefix<<<SCAN_TILES, 1024, 0, stream>>>(offsets, tilePre, cursor);
    edge_scatter<<<(N_EDGES + 255) / 256, 256, 0, stream>>>(dst, src, ew, cursor, srcp, ewp);

    // pack mu/ls weights to bf16 fragment order
    pack_w<<<128, 256, 0, stream>>>(mu_Wl, mu_Wr, ls_Wl, ls_Wr, Bpack);

    // conv1 (concat)
    gemm_k5<<<N_NODES, 256, 0, stream>>>(x0, c1_Wl, c1_bl, c1_Wr, c1_br, xl, xr);
    agg_fused<1><<<N_NODES / 4 + 1, 256, 0, stream>>>(xl, xr, c1_We, c1_att, offsets,
                                                      srcp, ewp, c1_bias, xB);

    // BN1 stats; apply+ReLU fused into pack
    bn1_reduce<<<782, 256, 0, stream>>>(xB, bn1sum, bn1sq);
    pack_x_bn<<<6256, 256, 0, stream>>>(xB, bn1sum, bn1sq, bn1g, bn1b, Apack);

    // mu conv (head-mean)
    gemm_mfma<<<782, 512, 0, stream>>>(Apack, Bpack, mu_bl, mu_br, xl, xr);
    agg_fused<0><<<N_NODES / 4 + 1, 256, 0, stream>>>(xl, xr, mu_We, mu_att, offsets,
                                                      srcp, ewp, mu_bias, out_mu);

    // log_std conv (head-mean)
    gemm_mfma<<<782, 512, 0, stream>>>(Apack, Bpack + 131072, ls_bl, ls_br, xl, xr);
    agg_fused<0><<<N_NODES / 4 + 1, 256, 0, stream>>>(xl, xr, ls_We, ls_att, offsets,
                                                      srcp, ewp, ls_bias, out_ls);
}

// Round 8
// 456.493 us; speedup vs baseline: 1.1108x; 1.1108x over previous
//
#include <hip/hip_runtime.h>
#include <math.h>

#define N_NODES 50000
#define N_EDGES 300000
#define BN_EPS 1e-5f
#define NEG_SLOPE 0.2f

// 50000 rows pad to 3128 row-blocks of 16 (50048)
#define RB_COUNT 3128
#define SCAN_TILES 49    // 49*1024 = 50176 >= N_NODES
#define BN1_BLOCKS 523   // 523*96 = 50208 >= N_NODES

typedef short bf8v __attribute__((ext_vector_type(8)));
typedef float f4v __attribute__((ext_vector_type(4)));
typedef unsigned short u8v __attribute__((ext_vector_type(8)));

__device__ inline unsigned short f2bf(float f) {
    union { float f; unsigned u; } c; c.f = f;
    unsigned r = c.u + 0x7fffu + ((c.u >> 16) & 1u);
    return (unsigned short)(r >> 16);
}
__device__ inline float bf2f(unsigned short u) {
    union { unsigned u; float f; } c; c.u = ((unsigned)u) << 16;
    return c.f;
}

// async global->LDS DMA, 16B per lane; LDS dest = ldsbase + lane*16 (wave-uniform base)
__device__ inline void async_copy16(void* lds, const void* g) {
    __builtin_amdgcn_global_load_lds(
        (const __attribute__((address_space(1))) unsigned int*)g,
        (__attribute__((address_space(3))) unsigned int*)lds, 16, 0, 0);
}

// ---------------- BN0 (5 columns), grid-parallel ----------------
__global__ void bn0_reduce(const float* __restrict__ h, float* __restrict__ acc /*[10]*/) {
    __shared__ float lds[4][10];
    int tid = threadIdx.x;
    int lane = tid & 63, wave = tid >> 6;
    float ls[5] = {0,0,0,0,0}, lq[5] = {0,0,0,0,0};
    for (int r = blockIdx.x * 256 + tid; r < N_NODES; r += 128 * 256) {
        #pragma unroll
        for (int k = 0; k < 5; k++) {
            float v = h[r*5 + k];
            ls[k] += v; lq[k] += v*v;
        }
    }
    #pragma unroll
    for (int k = 0; k < 5; k++) {
        #pragma unroll
        for (int m = 1; m <= 32; m <<= 1) {
            ls[k] += __shfl_xor(ls[k], m, 64);
            lq[k] += __shfl_xor(lq[k], m, 64);
        }
    }
    if (lane == 0) {
        #pragma unroll
        for (int k = 0; k < 5; k++) { lds[wave][k] = ls[k]; lds[wave][5+k] = lq[k]; }
    }
    __syncthreads();
    if (tid < 10) {
        float s = lds[0][tid] + lds[1][tid] + lds[2][tid] + lds[3][tid];
        atomicAdd(&acc[tid], s);
    }
}

__global__ void bn0_finalize(const float* __restrict__ acc, const float* __restrict__ g,
                             const float* __restrict__ b, float* __restrict__ ss) {
    int tid = threadIdx.x;
    if (tid < 5) {
        float mean = acc[tid] * (1.f / N_NODES);
        float var  = acc[5 + tid] * (1.f / N_NODES) - mean*mean;
        float sc = g[tid] * rsqrtf(var + BN_EPS);
        ss[tid]     = sc;
        ss[5 + tid] = b[tid] - mean * sc;
    }
}

__global__ void bn0_apply(const float* __restrict__ h, const float* __restrict__ ss,
                          float* __restrict__ x0) {
    int i = blockIdx.x * blockDim.x + threadIdx.x;
    if (i < N_NODES * 5) {
        int k = i % 5;
        x0[i] = h[i] * ss[k] + ss[5 + k];
    }
}

// ---------------- CSR build by dst ----------------
__global__ void edge_count(const int* __restrict__ dst, int* __restrict__ count) {
    int e = blockIdx.x * blockDim.x + threadIdx.x;
    if (e < N_EDGES) atomicAdd(&count[dst[e]], 1);
}

// two-level scan: per-tile local exclusive scan + tile totals
__global__ void local_scan(const int* __restrict__ count, int* __restrict__ offsets,
                           int* __restrict__ tileSum) {
    __shared__ int lds[1024];
    int tid = threadIdx.x;
    int i = blockIdx.x * 1024 + tid;
    int v = (i < N_NODES) ? count[i] : 0;
    lds[tid] = v;
    __syncthreads();
    #pragma unroll
    for (int off = 1; off < 1024; off <<= 1) {
        int t = (tid >= off) ? lds[tid - off] : 0;
        __syncthreads();
        lds[tid] += t;
        __syncthreads();
    }
    if (i < N_NODES) offsets[i] = lds[tid] - v;   // local exclusive
    if (tid == 1023) tileSum[blockIdx.x] = lds[1023];
}

__global__ void tile_scan(const int* __restrict__ tileSum, int* __restrict__ tilePrefix,
                          int* __restrict__ offsets) {
    int lane = threadIdx.x;
    int v = (lane < SCAN_TILES) ? tileSum[lane] : 0;
    int inc = v;
    #pragma unroll
    for (int off = 1; off < 64; off <<= 1) {
        int t = __shfl_up(inc, off, 64);
        if (lane >= off) inc += t;
    }
    int excl = inc - v;
    if (lane < SCAN_TILES) tilePrefix[lane] = excl;
    if (lane == SCAN_TILES - 1) offsets[N_NODES] = inc;
}

__global__ void add_prefix(int* __restrict__ offsets, const int* __restrict__ tilePrefix,
                           int* __restrict__ cursor) {
    int i = blockIdx.x * 1024 + threadIdx.x;
    if (i < N_NODES) {
        int o = offsets[i] + tilePrefix[blockIdx.x];
        offsets[i] = o;
        cursor[i] = o;
    }
}

// scatter edge ids into CSR order; also materialize src and edge-weight in CSR order
__global__ void edge_scatter(const int* __restrict__ dst, const int* __restrict__ src,
                             const float* __restrict__ ew, int* __restrict__ cursor,
                             int* __restrict__ srcp, float* __restrict__ ewp) {
    int e = blockIdx.x * blockDim.x + threadIdx.x;
    if (e < N_EDGES) {
        int pos = atomicAdd(&cursor[dst[e]], 1);
        srcp[pos] = src[e];
        ewp[pos] = ew[e];
    }
}

// ---------------- conv1 linear (K=5), bf16 output ----------------
__global__ void gemm_k5(const float* __restrict__ x0,
                        const float* __restrict__ Wl, const float* __restrict__ bl,
                        const float* __restrict__ Wr, const float* __restrict__ br,
                        unsigned short* __restrict__ xl, unsigned short* __restrict__ xr) {
    int n = blockIdx.x;
    int c = threadIdx.x;
    float a0 = x0[n*5+0], a1 = x0[n*5+1], a2 = x0[n*5+2], a3 = x0[n*5+3], a4 = x0[n*5+4];
    float l = bl[c] + a0*Wl[c] + a1*Wl[256+c] + a2*Wl[512+c] + a3*Wl[768+c] + a4*Wl[1024+c];
    float r = br[c] + a0*Wr[c] + a1*Wr[256+c] + a2*Wr[512+c] + a3*Wr[768+c] + a4*Wr[1024+c];
    xl[n*256 + c] = f2bf(l);
    xr[n*256 + c] = f2bf(r);
}

// ---------------- pack X with fused BN1(scale/shift)+ReLU -> bf16 A-fragment order ------
__global__ void pack_x_bn(const float* __restrict__ x, const float* __restrict__ ss1,
                          unsigned short* __restrict__ ap) {
    int t = blockIdx.x * 256 + threadIdx.x;   // RB_COUNT*8*64 = 1601536 threads exact
    int lane = t & 63;
    int kc = (t >> 6) & 7;
    int rb = t >> 9;
    int row = rb * 16 + (lane & 15);
    int k0 = kc * 32 + (lane >> 4) * 8;
    union { unsigned short h[8]; uint4 u; } tmp;
    if (row < N_NODES) {
        const float* s = x + (size_t)row * 256 + k0;
        #pragma unroll
        for (int j = 0; j < 8; j++) {
            int c = k0 + j;
            float v = s[j] * ss1[c] + ss1[256 + c];
            v = v > 0.f ? v : 0.f;
            tmp.h[j] = f2bf(v);
        }
    } else {
        #pragma unroll
        for (int j = 0; j < 8; j++) tmp.h[j] = 0;
    }
    *reinterpret_cast<uint4*>(ap + (size_t)t * 8) = tmp.u;
}

// ---------------- pack W for both convs (fp32 -> bf16 MFMA B-fragment order) ----------------
__global__ void pack_w(const float* __restrict__ Wl0, const float* __restrict__ Wr0,
                       const float* __restrict__ Wl1, const float* __restrict__ Wr1,
                       unsigned short* __restrict__ bp) {
    int t = blockIdx.x * 256 + threadIdx.x;   // 2*8*32*64 = 32768 threads exact
    int lane = t & 63;
    int nt = (t >> 6) & 31;
    int kc = (t >> 11) & 7;
    int conv = t >> 14;
    int col = nt * 16 + (lane & 15);
    int k0 = kc * 32 + (lane >> 4) * 8;
    const float* W = conv ? (col < 256 ? Wl1 : Wr1) : (col < 256 ? Wl0 : Wr0);
    int c = col & 255;
    union { unsigned short h[8]; uint4 u; } tmp;
    #pragma unroll
    for (int j = 0; j < 8; j++) tmp.h[j] = f2bf(W[(size_t)(k0 + j) * 256 + c]);
    *reinterpret_cast<uint4*>(bp + (size_t)t * 8) = tmp.u;
}

// ---------------- big linear via MFMA, LDS-staged B (double-buffered), bf16 output -------
__global__ __launch_bounds__(512) void gemm_mfma(const unsigned short* __restrict__ ap,
        const unsigned short* __restrict__ bp,
        const float* __restrict__ bl, const float* __restrict__ br,
        unsigned short* __restrict__ xl, unsigned short* __restrict__ xr) {
    __shared__ unsigned short Bs[2][32][512];   // [buf][frag f=h*16+t][lane*8]
    int lane = threadIdx.x & 63;
    int wave = threadIdx.x >> 6;
    int h = wave & 1;
    int rb = blockIdx.x * 4 + (wave >> 1);

    const unsigned short* aptr = ap + (size_t)rb * 4096 + lane * 8;
    const unsigned short* bsrc = bp + lane * 8;

    // stage B[kc] into Bs[buf]: this wave's 4 frags (f = wave*4 + j; f -> offset f*512)
    auto stage = [&](int buf, int kc) {
        #pragma unroll
        for (int j = 0; j < 4; j++) {
            int f = wave * 4 + j;
            async_copy16(&Bs[buf][f][lane * 8], bsrc + (size_t)kc * 16384 + f * 512);
        }
    };
    stage(0, 0);

    // preload all A fragments (8 kc x 16B/lane = 32 VGPRs)
    bf8v a[8];
    #pragma unroll
    for (int kc = 0; kc < 8; kc++) a[kc] = *reinterpret_cast<const bf8v*>(aptr + kc * 512);

    f4v acc[16];
    #pragma unroll
    for (int t = 0; t < 16; t++) acc[t] = (f4v){0.f, 0.f, 0.f, 0.f};

    for (int kc = 0; kc < 8; kc++) {
        __syncthreads();                       // staging of buf kc&1 complete; prev buf free
        if (kc < 7) stage((kc + 1) & 1, kc + 1);
        const unsigned short* bb = &Bs[kc & 1][h * 16][lane * 8];
        #pragma unroll
        for (int t = 0; t < 16; t++) {
            bf8v b = *reinterpret_cast<const bf8v*>(bb + t * 512);
            acc[t] = __builtin_amdgcn_mfma_f32_16x16x32_bf16(a[kc], b, acc[t], 0, 0, 0);
        }
    }

    int c15 = lane & 15;
    int row0 = rb * 16 + (lane >> 4) * 4;
    unsigned short* outp = h ? xr : xl;
    const float* bias = h ? br : bl;
    #pragma unroll
    for (int t = 0; t < 16; t++) {
        int col = t * 16 + c15;
        float bv = bias[col];
        #pragma unroll
        for (int r = 0; r < 4; r++) {
            int row = row0 + r;
            if (row < N_NODES) outp[(size_t)row * 256 + col] = f2bf(acc[t][r] + bv);
        }
    }
}

// ---------------- fused GATv2 edge phase: alpha + online-softmax + aggregate ----------
// one wave per node, TWO edge streams per wave (lanes 0-31: even edges, 32-63: odd edges).
// Within a stream: 16 lanes per head, 8 channels per lane (16B gathers).
// Streams keep independent online-softmax state, merged at the end via shfl_xor 32.
template <int CONCAT>
__global__ void agg_fused(const unsigned short* __restrict__ xl,
                          const unsigned short* __restrict__ xr,
                          const float* __restrict__ We, const float* __restrict__ att,
                          const int* __restrict__ offsets, const int* __restrict__ srcp,
                          const float* __restrict__ ewp, const float* __restrict__ bias,
                          float* __restrict__ out) {
    int n = blockIdx.x * 4 + (threadIdx.x >> 6);
    int lane = threadIdx.x & 63;
    if (n >= N_NODES) return;
    int half = lane >> 5;                              // edge stream (even/odd)
    int sub  = lane & 31;
    int cb   = (sub >> 4) * 128 + (sub & 15) * 8;      // 8-channel base in [0,256)
    float wv[8], av[8], rv[8];
    *(float4*)&wv[0] = *(const float4*)(We + cb);
    *(float4*)&wv[4] = *(const float4*)(We + cb + 4);
    *(float4*)&av[0] = *(const float4*)(att + cb);
    *(float4*)&av[4] = *(const float4*)(att + cb + 4);
    u8v r8 = *(const u8v*)(xr + (size_t)n * 256 + cb);
    #pragma unroll
    for (int j = 0; j < 8; j++) rv[j] = bf2f(r8[j]);
    int beg = offsets[n], end = offsets[n + 1];
    float mrun = -1e30f, den = 0.f;
    float acc[8];
    #pragma unroll
    for (int j = 0; j < 8; j++) acc[j] = 0.f;

    int i = beg + half;
    int sN = 0; float wN = 0.f;
    u8v lN;
    #pragma unroll
    for (int j = 0; j < 8; j++) lN[j] = 0;
    if (i < end) {
        sN = srcp[i]; wN = ewp[i];
        lN = *(const u8v*)(xl + (size_t)sN * 256 + cb);
    }
    for (; i < end; i += 2) {
        u8v l8 = lN; float w = wN;
        int nx = i + 2;
        if (nx < end) {                              // distance-1 prefetch
            sN = srcp[nx]; wN = ewp[nx];
            lN = *(const u8v*)(xl + (size_t)sN * 256 + cb);
        }
        float lv[8];
        float a = 0.f;
        #pragma unroll
        for (int j = 0; j < 8; j++) {
            lv[j] = bf2f(l8[j]);
            float v = lv[j] + rv[j] + w * wv[j];
            v = fmaxf(v, NEG_SLOPE * v);             // leaky relu (slope<1)
            a += v * av[j];
        }
        a += __shfl_xor(a, 1, 64);
        a += __shfl_xor(a, 2, 64);
        a += __shfl_xor(a, 4, 64);
        a += __shfl_xor(a, 8, 64);                   // per-head alpha (16-lane groups)
        float nm = fmaxf(mrun, a);
        float scl = __expf(mrun - nm);
        float p = __expf(a - nm);
        den = den * scl + p;
        #pragma unroll
        for (int j = 0; j < 8; j++) acc[j] = acc[j] * scl + p * lv[j];
        mrun = nm;
    }
    // merge even/odd streams
    {
        float mo  = __shfl_xor(mrun, 32, 64);
        float dno = __shfl_xor(den, 32, 64);
        float nm = fmaxf(mrun, mo);
        float s0 = __expf(mrun - nm);
        float s1 = __expf(mo - nm);
        den = den * s0 + dno * s1;
        #pragma unroll
        for (int j = 0; j < 8; j++) {
            float ao = __shfl_xor(acc[j], 32, 64);
            acc[j] = acc[j] * s0 + ao * s1;
        }
    }
    float inv = 1.f / (den + 1e-16f);
    if (CONCAT) {
        if (lane < 32) {
            float o[8];
            #pragma unroll
            for (int j = 0; j < 8; j++) o[j] = acc[j] * inv + bias[cb + j];
            *(float4*)(out + (size_t)n * 256 + cb)     = *(float4*)&o[0];
            *(float4*)(out + (size_t)n * 256 + cb + 4) = *(float4*)&o[4];
        }
    } else {
        float o[8];
        #pragma unroll
        for (int j = 0; j < 8; j++) o[j] = acc[j] * inv;
        float po[8];
        #pragma unroll
        for (int j = 0; j < 8; j++) po[j] = __shfl_xor(o[j], 16, 64);  // other head, same ch
        if (lane < 16) {
            int c0 = (lane & 15) * 8;
            float r[8];
            #pragma unroll
            for (int j = 0; j < 8; j++) r[j] = (o[j] + po[j]) * 0.5f + bias[c0 + j];
            *(float4*)(out + (size_t)n * 128 + c0)     = *(float4*)&r[0];
            *(float4*)(out + (size_t)n * 128 + c0 + 4) = *(float4*)&r[4];
        }
    }
}

// ---------------- BN1 stats, phase 1: per-block partials (NO atomics) ----------------
// 523 blocks x 96 rows. Thread = (col-group of 4 via float4, row phase = tid>>6).
// Output: part[block][0..255]=sum, part[block][256..511]=sumsq.
__global__ void bn1_reduce(const float* __restrict__ x, float* __restrict__ part) {
    __shared__ float lds[256][9];   // stride 9 floats -> no bank conflicts
    int tid = threadIdx.x;
    int cg = tid & 63;              // col group: cols cg*4 .. cg*4+3
    int ph = tid >> 6;              // row phase 0..3
    int r0 = blockIdx.x * 96;
    float s[4] = {0,0,0,0}, q[4] = {0,0,0,0};
    #pragma unroll
    for (int it = 0; it < 24; it++) {
        int row = r0 + it * 4 + ph;
        if (row < N_NODES) {
            float4 v = *(const float4*)(x + (size_t)row * 256 + cg * 4);
            s[0] += v.x; s[1] += v.y; s[2] += v.z; s[3] += v.w;
            q[0] += v.x*v.x; q[1] += v.y*v.y; q[2] += v.z*v.z; q[3] += v.w*v.w;
        }
    }
    #pragma unroll
    for (int j = 0; j < 4; j++) { lds[tid][j] = s[j]; lds[tid][4+j] = q[j]; }
    __syncthreads();
    if (tid < 64) {
        float4 sv, qv;
        float* svp = (float*)&sv; float* qvp = (float*)&qv;
        #pragma unroll
        for (int j = 0; j < 4; j++) {
            svp[j] = lds[tid][j] + lds[tid+64][j] + lds[tid+128][j] + lds[tid+192][j];
            qvp[j] = lds[tid][4+j] + lds[tid+64][4+j] + lds[tid+128][4+j] + lds[tid+192][4+j];
        }
        *(float4*)(part + (size_t)blockIdx.x * 512 + cg * 4) = sv;
        *(float4*)(part + (size_t)blockIdx.x * 512 + 256 + cg * 4) = qv;
    }
}

// ---------------- BN1 stats, phase 2: reduce partials, emit scale/shift ----------------
// 8 blocks x 256 threads; block handles 32 columns; threads split the 523 partials 8 ways.
__global__ void bn1_finalize(const float* __restrict__ part, const float* __restrict__ g,
                             const float* __restrict__ b, float* __restrict__ ss1) {
    __shared__ float lds[8][64];
    int t = threadIdx.x;
    int c = blockIdx.x * 32 + (t & 31);
    int ph = t >> 5;                 // 0..7
    float s = 0.f, q = 0.f;
    for (int bi = ph; bi < BN1_BLOCKS; bi += 8) {
        s += part[(size_t)bi * 512 + c];
        q += part[(size_t)bi * 512 + 256 + c];
    }
    lds[ph][t & 31] = s;
    lds[ph][32 + (t & 31)] = q;
    __syncthreads();
    if (t < 32) {
        float ss = 0.f, qq = 0.f;
        #pragma unroll
        for (int p = 0; p < 8; p++) { ss += lds[p][t]; qq += lds[p][32 + t]; }
        float mean = ss * (1.f / N_NODES);
        float var  = qq * (1.f / N_NODES) - mean * mean;
        float sc = g[c] * rsqrtf(var + BN_EPS);
        ss1[c] = sc;
        ss1[256 + c] = b[c] - mean * sc;
    }
}

extern "C" void kernel_launch(void* const* d_in, const int* in_sizes, int n_in,
                              void* d_out, int out_size, void* d_ws, size_t ws_size,
                              hipStream_t stream) {
    const float* h          = (const float*)d_in[0];
    const int*   edge_index = (const int*)d_in[1];
    const int*   src = edge_index;
    const int*   dst = edge_index + N_EDGES;
    const float* ew   = (const float*)d_in[2];
    const float* bn0g = (const float*)d_in[3];
    const float* bn0b = (const float*)d_in[4];
    const float* bn1g = (const float*)d_in[5];
    const float* bn1b = (const float*)d_in[6];
    const float* c1_Wl = (const float*)d_in[7];
    const float* c1_bl = (const float*)d_in[8];
    const float* c1_Wr = (const float*)d_in[9];
    const float* c1_br = (const float*)d_in[10];
    const float* c1_We = (const float*)d_in[11];
    const float* c1_att = (const float*)d_in[12];
    const float* c1_bias = (const float*)d_in[13];
    const float* mu_Wl = (const float*)d_in[14];
    const float* mu_bl = (const float*)d_in[15];
    const float* mu_Wr = (const float*)d_in[16];
    const float* mu_br = (const float*)d_in[17];
    const float* mu_We = (const float*)d_in[18];
    const float* mu_att = (const float*)d_in[19];
    const float* mu_bias = (const float*)d_in[20];
    const float* ls_Wl = (const float*)d_in[21];
    const float* ls_bl = (const float*)d_in[22];
    const float* ls_Wr = (const float*)d_in[23];
    const float* ls_br = (const float*)d_in[24];
    const float* ls_We = (const float*)d_in[25];
    const float* ls_att = (const float*)d_in[26];
    const float* ls_bias = (const float*)d_in[27];

    float* out_mu = (float*)d_out;
    float* out_ls = (float*)d_out + (size_t)N_NODES * 128;

    // workspace carve-up (256B aligned blocks)
    char* ws = (char*)d_ws;
    size_t off = 0;
    auto alloc = [&](size_t bytes) -> void* {
        void* p = ws + off;
        off += (bytes + 255) / 256 * 256;
        return p;
    };
    float* x0      = (float*)alloc((size_t)N_NODES * 5 * 4);
    unsigned short* xl = (unsigned short*)alloc((size_t)N_NODES * 256 * 2);
    unsigned short* xr = (unsigned short*)alloc((size_t)N_NODES * 256 * 2);
    float* xB      = (float*)alloc((size_t)N_NODES * 256 * 4);
    float* bn0acc  = (float*)alloc(10 * 4);
    float* bn0ss   = (float*)alloc(10 * 4);
    float* bn1part = (float*)alloc((size_t)BN1_BLOCKS * 512 * 4);   // 1.07 MB
    float* bn1ss   = (float*)alloc(512 * 4);
    int*   count   = (int*)alloc((size_t)N_NODES * 4);
    int*   offsets = (int*)alloc((size_t)(N_NODES + 1) * 4);
    int*   cursor  = (int*)alloc((size_t)N_NODES * 4);
    int*   srcp    = (int*)alloc((size_t)N_EDGES * 4);
    float* ewp     = (float*)alloc((size_t)N_EDGES * 4);
    int*   tileSum = (int*)alloc((size_t)SCAN_TILES * 4);
    int*   tilePre = (int*)alloc((size_t)SCAN_TILES * 4);
    unsigned short* Apack = (unsigned short*)alloc((size_t)RB_COUNT * 4096 * 2);  // 25.6 MB
    unsigned short* Bpack = (unsigned short*)alloc((size_t)2 * 131072 * 2);       // 512 KB

    hipMemsetAsync(count, 0, (size_t)N_NODES * 4, stream);
    hipMemsetAsync(bn0acc, 0, 10 * 4, stream);

    // BN0 (grid-parallel)
    bn0_reduce<<<128, 256, 0, stream>>>(h, bn0acc);
    bn0_finalize<<<1, 64, 0, stream>>>(bn0acc, bn0g, bn0b, bn0ss);
    bn0_apply<<<(N_NODES * 5 + 255) / 256, 256, 0, stream>>>(h, bn0ss, x0);

    // CSR by dst (shared by all 3 convs) — two-level parallel scan
    edge_count<<<(N_EDGES + 255) / 256, 256, 0, stream>>>(dst, count);
    local_scan<<<SCAN_TILES, 1024, 0, stream>>>(count, offsets, tileSum);
    tile_scan<<<1, 64, 0, stream>>>(tileSum, tilePre, offsets);
    add_prefix<<<SCAN_TILES, 1024, 0, stream>>>(offsets, tilePre, cursor);
    edge_scatter<<<(N_EDGES + 255) / 256, 256, 0, stream>>>(dst, src, ew, cursor, srcp, ewp);

    // pack mu/ls weights to bf16 fragment order
    pack_w<<<128, 256, 0, stream>>>(mu_Wl, mu_Wr, ls_Wl, ls_Wr, Bpack);

    // conv1 (concat)
    gemm_k5<<<N_NODES, 256, 0, stream>>>(x0, c1_Wl, c1_bl, c1_Wr, c1_br, xl, xr);
    agg_fused<1><<<N_NODES / 4 + 1, 256, 0, stream>>>(xl, xr, c1_We, c1_att, offsets,
                                                      srcp, ewp, c1_bias, xB);

    // BN1 stats (atomic-free two-phase); apply+ReLU fused into pack
    bn1_reduce<<<BN1_BLOCKS, 256, 0, stream>>>(xB, bn1part);
    bn1_finalize<<<8, 256, 0, stream>>>(bn1part, bn1g, bn1b, bn1ss);
    pack_x_bn<<<6256, 256, 0, stream>>>(xB, bn1ss, Apack);

    // mu conv (head-mean)
    gemm_mfma<<<782, 512, 0, stream>>>(Apack, Bpack, mu_bl, mu_br, xl, xr);
    agg_fused<0><<<N_NODES / 4 + 1, 256, 0, stream>>>(xl, xr, mu_We, mu_att, offsets,
                                                      srcp, ewp, mu_bias, out_mu);

    // log_std conv (head-mean)
    gemm_mfma<<<782, 512, 0, stream>>>(Apack, Bpack + 131072, ls_bl, ls_br, xl, xr);
    agg_fused<0><<<N_NODES / 4 + 1, 256, 0, stream>>>(xl, xr, ls_We, ls_att, offsets,
                                                      srcp, ewp, ls_bias, out_ls);
}